// Round 1
// baseline (3115.855 us; speedup 1.0000x reference)
//
#include <hip/hip_runtime.h>
#include <math.h>

#define C 64
#define R 32
#define TE 32
#define CUTOFF 5.0f

__device__ __forceinline__ float silu(float x) { return x / (1.0f + __expf(-x)); }

// ---------------------------------------------------------------------------
// Node prep: Xn = X/(||X||^2+1); decompose -> compressed comps (i, a[3], s[6]);
// channel-mix comps with Wt[0..2]; store Xn[N][C][9] and nf[N][C][10].
// Block = 256 threads = 4 nodes x 64 channels.
// ---------------------------------------------------------------------------
__global__ __launch_bounds__(256) void k_node_prep(
    const float* __restrict__ X, const float* __restrict__ Wt,
    float* __restrict__ Xn, float* __restrict__ nf, int N) {
  const int ln = threadIdx.x >> 6;   // 0..3 node within block
  const int c  = threadIdx.x & 63;   // channel
  const int node = blockIdx.x * 4 + ln;
  __shared__ float comps[4][C][10];

  if (node < N) {
    const float* xp = X + ((size_t)node * C + c) * 9;
    float x[9]; float nrm = 0.f;
#pragma unroll
    for (int j = 0; j < 9; j++) { x[j] = xp[j]; nrm += x[j] * x[j]; }
    const float inv = 1.0f / (nrm + 1.0f);
#pragma unroll
    for (int j = 0; j < 9; j++) x[j] *= inv;
    float* xnp = Xn + ((size_t)node * C + c) * 9;
#pragma unroll
    for (int j = 0; j < 9; j++) xnp[j] = x[j];
    const float tr3 = (x[0] + x[4] + x[8]) * (1.f / 3.f);
    float* cp = comps[ln][c];
    cp[0] = tr3;
    cp[1] = 0.5f * (x[1] - x[3]);   // a01
    cp[2] = 0.5f * (x[2] - x[6]);   // a02
    cp[3] = 0.5f * (x[5] - x[7]);   // a12
    cp[4] = x[0] - tr3;             // s00
    cp[5] = x[4] - tr3;             // s11
    cp[6] = x[8] - tr3;             // s22
    cp[7] = 0.5f * (x[1] + x[3]);   // s01
    cp[8] = 0.5f * (x[2] + x[6]);   // s02
    cp[9] = 0.5f * (x[5] + x[7]);   // s12
  }
  __syncthreads();
  if (node < N) {
    const float* W0 = Wt;
    const float* W1 = Wt + C * C;
    const float* W2 = Wt + 2 * C * C;
    float o[10];
#pragma unroll
    for (int j = 0; j < 10; j++) o[j] = 0.f;
    for (int k = 0; k < C; k++) {
      const float w0 = W0[k * C + c];
      const float w1 = W1[k * C + c];
      const float w2 = W2[k * C + c];
      const float* cp = comps[ln][k];
      o[0] += cp[0] * w0;
      o[1] += cp[1] * w1; o[2] += cp[2] * w1; o[3] += cp[3] * w1;
      o[4] += cp[4] * w2; o[5] += cp[5] * w2; o[6] += cp[6] * w2;
      o[7] += cp[7] * w2; o[8] += cp[8] * w2; o[9] += cp[9] * w2;
    }
    float* np_ = nf + ((size_t)node * C + c) * 10;
#pragma unroll
    for (int j = 0; j < 10; j++) np_[j] = o[j];
  }
}

// ---------------------------------------------------------------------------
// Fused edge MLP + message scatter. Block = 256 threads, TE=32 edges.
// MLP: attr[32] -> 64 -> 128 -> 192 (silu each), scaled by cosine cutoff.
// Message: msg[src] += f0*I[dst] + f1*A[dst] + f2*S[dst] (per channel 3x3).
// ---------------------------------------------------------------------------
__global__ __launch_bounds__(256) void k_edge(
    const int* __restrict__ ei, const float* __restrict__ ew,
    const float* __restrict__ ea,
    const float* __restrict__ W1, const float* __restrict__ b1,
    const float* __restrict__ W2, const float* __restrict__ b2,
    const float* __restrict__ W3, const float* __restrict__ b3,
    const float* __restrict__ nf, float* __restrict__ msg, int E) {
  __shared__ float attr[TE][R];        // 4 KB
  __shared__ float h1[TE][C];          // 8 KB
  __shared__ float h2[TE][2 * C];      // 16 KB
  __shared__ float h3[TE][3 * C];      // 24 KB
  __shared__ float cw[TE];
  const int e0 = blockIdx.x * TE;
  const int tid = threadIdx.x;

  for (int i = tid; i < TE * R; i += 256) {
    int e = i / R, k = i % R;
    int ge = e0 + e;
    attr[e][k] = (ge < E) ? ea[(size_t)ge * R + k] : 0.f;
  }
  if (tid < TE) {
    int ge = e0 + tid;
    float w = (ge < E) ? ew[ge] : 0.f;
    float cc = 0.5f * (cosf(w * (3.14159265358979323846f / CUTOFF)) + 1.0f);
    cw[tid] = (w < CUTOFF) ? cc : 0.f;
  }
  __syncthreads();
  // h1 = silu(attr @ W1 + b1)   [TE x 64]
  for (int i = tid; i < TE * C; i += 256) {
    int e = i / C, l = i % C;
    float acc = b1[l];
    for (int k = 0; k < R; k++) acc += attr[e][k] * W1[k * C + l];
    h1[e][l] = silu(acc);
  }
  __syncthreads();
  // h2 = silu(h1 @ W2 + b2)     [TE x 128]
  for (int i = tid; i < TE * 2 * C; i += 256) {
    int e = i / (2 * C), l = i % (2 * C);
    float acc = b2[l];
    for (int k = 0; k < C; k++) acc += h1[e][k] * W2[k * 2 * C + l];
    h2[e][l] = silu(acc);
  }
  __syncthreads();
  // h3 = silu(h2 @ W3 + b3)     [TE x 192]
  for (int i = tid; i < TE * 3 * C; i += 256) {
    int e = i / (3 * C), l = i % (3 * C);
    float acc = b3[l];
    for (int k = 0; k < 2 * C; k++) acc += h2[e][k] * W3[k * 3 * C + l];
    h3[e][l] = silu(acc);
  }
  __syncthreads();
  // message: one (edge, channel) per thread iter
  for (int i = tid; i < TE * C; i += 256) {
    int e = i / C, c = i % C;
    int ge = e0 + e;
    if (ge >= E) continue;
    int src = ei[ge];
    int dst = ei[E + ge];
    float cwv = cw[e];
    float f0 = h3[e][3 * c + 0] * cwv;
    float f1 = h3[e][3 * c + 1] * cwv;
    float f2 = h3[e][3 * c + 2] * cwv;
    const float* p = nf + ((size_t)dst * C + c) * 10;
    float iv = p[0], a0 = p[1], a1 = p[2], a2 = p[3];
    float s00 = p[4], s11 = p[5], s22 = p[6], s01 = p[7], s02 = p[8], s12 = p[9];
    float d0 = f0 * iv;
    float A01 = f1 * a0, A02 = f1 * a1, A12 = f1 * a2;
    float S01 = f2 * s01, S02 = f2 * s02, S12 = f2 * s12;
    float m[9];
    m[0] = d0 + f2 * s00; m[4] = d0 + f2 * s11; m[8] = d0 + f2 * s22;
    m[1] = A01 + S01; m[3] = S01 - A01;
    m[2] = A02 + S02; m[6] = S02 - A02;
    m[5] = A12 + S12; m[7] = S12 - A12;
    float* mp_ = msg + ((size_t)src * C + c) * 9;
#pragma unroll
    for (int j = 0; j < 9; j++) atomicAdd(mp_ + j, m[j]);
  }
}

// ---------------------------------------------------------------------------
// Output: M = msg@Y + Y@msg; decompose/normalize; mix with Wt[3..5];
// out = Xn + dX + dX@dX.  Block = 4 nodes x 64 channels.
// ---------------------------------------------------------------------------
__global__ __launch_bounds__(256) void k_out(
    const float* __restrict__ msg, const float* __restrict__ nf,
    const float* __restrict__ Xn, const float* __restrict__ Wt,
    float* __restrict__ out, int N) {
  const int ln = threadIdx.x >> 6;
  const int c  = threadIdx.x & 63;
  const int node = blockIdx.x * 4 + ln;
  __shared__ float comps[4][C][10];

  if (node < N) {
    const float* p = nf + ((size_t)node * C + c) * 10;
    float iv = p[0], a0 = p[1], a1 = p[2], a2 = p[3];
    float s00 = p[4], s11 = p[5], s22 = p[6], s01 = p[7], s02 = p[8], s12 = p[9];
    float Y[9] = { iv + s00, a0 + s01, a1 + s02,
                   s01 - a0, iv + s11, a2 + s12,
                   s02 - a1, s12 - a2, iv + s22 };
    const float* mq = msg + ((size_t)node * C + c) * 9;
    float G[9];
#pragma unroll
    for (int j = 0; j < 9; j++) G[j] = mq[j];
    float M[9];
#pragma unroll
    for (int i2 = 0; i2 < 3; i2++)
#pragma unroll
      for (int j2 = 0; j2 < 3; j2++) {
        float acc = 0.f;
#pragma unroll
        for (int k2 = 0; k2 < 3; k2++)
          acc += G[i2 * 3 + k2] * Y[k2 * 3 + j2] + Y[i2 * 3 + k2] * G[k2 * 3 + j2];
        M[i2 * 3 + j2] = acc;
      }
    float nrm = 0.f;
#pragma unroll
    for (int j = 0; j < 9; j++) nrm += M[j] * M[j];
    const float inv = 1.0f / (nrm + 1.0f);
    const float tr3 = (M[0] + M[4] + M[8]) * (1.f / 3.f);
    float* cp = comps[ln][c];
    cp[0] = tr3 * inv;
    cp[1] = 0.5f * (M[1] - M[3]) * inv;
    cp[2] = 0.5f * (M[2] - M[6]) * inv;
    cp[3] = 0.5f * (M[5] - M[7]) * inv;
    cp[4] = (M[0] - tr3) * inv;
    cp[5] = (M[4] - tr3) * inv;
    cp[6] = (M[8] - tr3) * inv;
    cp[7] = 0.5f * (M[1] + M[3]) * inv;
    cp[8] = 0.5f * (M[2] + M[6]) * inv;
    cp[9] = 0.5f * (M[5] + M[7]) * inv;
  }
  __syncthreads();
  if (node < N) {
    const float* W3 = Wt + 3 * C * C;
    const float* W4 = Wt + 4 * C * C;
    const float* W5 = Wt + 5 * C * C;
    float o[10];
#pragma unroll
    for (int j = 0; j < 10; j++) o[j] = 0.f;
    for (int k = 0; k < C; k++) {
      const float w3 = W3[k * C + c];
      const float w4 = W4[k * C + c];
      const float w5 = W5[k * C + c];
      const float* cp = comps[ln][k];
      o[0] += cp[0] * w3;
      o[1] += cp[1] * w4; o[2] += cp[2] * w4; o[3] += cp[3] * w4;
      o[4] += cp[4] * w5; o[5] += cp[5] * w5; o[6] += cp[6] * w5;
      o[7] += cp[7] * w5; o[8] += cp[8] * w5; o[9] += cp[9] * w5;
    }
    float dX[9] = { o[0] + o[4], o[1] + o[7], o[2] + o[8],
                    o[7] - o[1], o[0] + o[5], o[3] + o[9],
                    o[8] - o[2], o[9] - o[3], o[0] + o[6] };
    float dd[9];
#pragma unroll
    for (int i2 = 0; i2 < 3; i2++)
#pragma unroll
      for (int j2 = 0; j2 < 3; j2++) {
        float acc = 0.f;
#pragma unroll
        for (int k2 = 0; k2 < 3; k2++) acc += dX[i2 * 3 + k2] * dX[k2 * 3 + j2];
        dd[i2 * 3 + j2] = acc;
      }
    const float* xnp = Xn + ((size_t)node * C + c) * 9;
    float* op = out + ((size_t)node * C + c) * 9;
#pragma unroll
    for (int j = 0; j < 9; j++) op[j] = xnp[j] + dX[j] + dd[j];
  }
}

extern "C" void kernel_launch(void* const* d_in, const int* in_sizes, int n_in,
                              void* d_out, int out_size, void* d_ws, size_t ws_size,
                              hipStream_t stream) {
  const float* X  = (const float*)d_in[0];
  const int*   ei = (const int*)d_in[1];
  const float* ew = (const float*)d_in[2];
  const float* ea = (const float*)d_in[3];
  const float* W1 = (const float*)d_in[4];
  const float* b1 = (const float*)d_in[5];
  const float* W2 = (const float*)d_in[6];
  const float* b2 = (const float*)d_in[7];
  const float* W3 = (const float*)d_in[8];
  const float* b3 = (const float*)d_in[9];
  const float* Wt = (const float*)d_in[10];
  const int N = in_sizes[0] / (C * 9);
  const int E = in_sizes[1] / 2;

  float* nf  = (float*)d_ws;                    // [N][C][10]
  float* Xn  = nf + (size_t)N * C * 10;         // [N][C][9]
  float* msg = Xn + (size_t)N * C * 9;          // [N][C][9]

  hipMemsetAsync(msg, 0, (size_t)N * C * 9 * sizeof(float), stream);
  k_node_prep<<<(N + 3) / 4, 256, 0, stream>>>(X, Wt, Xn, nf, N);
  k_edge<<<(E + TE - 1) / TE, 256, 0, stream>>>(ei, ew, ea, W1, b1, W2, b2, W3, b3, nf, msg, E);
  k_out<<<(N + 3) / 4, 256, 0, stream>>>(msg, nf, Xn, Wt, (float*)d_out, N);
}

// Round 2
// 368.170 us; speedup vs baseline: 8.4631x; 8.4631x over previous
//
#include <hip/hip_runtime.h>
#include <math.h>

#define C 64
#define R 32
#define CUTOFF 5.0f
#define PI_F 3.14159265358979323846f

__device__ __forceinline__ float silu(float x) { return x / (1.0f + __expf(-x)); }

// ---------------------------------------------------------------------------
// Node prep: Xn = X/(||X||^2+1); decompose -> compressed comps (i, a[3], s[6]);
// channel-mix comps with Wt[0..2]; store Xn[N][C][9] and nf[N][C][10].
// Block = 256 threads = 4 nodes x 64 channels.
// ---------------------------------------------------------------------------
__global__ __launch_bounds__(256) void k_node_prep(
    const float* __restrict__ X, const float* __restrict__ Wt,
    float* __restrict__ Xn, float* __restrict__ nf, int N) {
  const int ln = threadIdx.x >> 6;
  const int c  = threadIdx.x & 63;
  const int node = blockIdx.x * 4 + ln;
  __shared__ float comps[4][C][10];

  if (node < N) {
    const float* xp = X + ((size_t)node * C + c) * 9;
    float x[9]; float nrm = 0.f;
#pragma unroll
    for (int j = 0; j < 9; j++) { x[j] = xp[j]; nrm += x[j] * x[j]; }
    const float inv = 1.0f / (nrm + 1.0f);
#pragma unroll
    for (int j = 0; j < 9; j++) x[j] *= inv;
    float* xnp = Xn + ((size_t)node * C + c) * 9;
#pragma unroll
    for (int j = 0; j < 9; j++) xnp[j] = x[j];
    const float tr3 = (x[0] + x[4] + x[8]) * (1.f / 3.f);
    float* cp = comps[ln][c];
    cp[0] = tr3;
    cp[1] = 0.5f * (x[1] - x[3]);
    cp[2] = 0.5f * (x[2] - x[6]);
    cp[3] = 0.5f * (x[5] - x[7]);
    cp[4] = x[0] - tr3;
    cp[5] = x[4] - tr3;
    cp[6] = x[8] - tr3;
    cp[7] = 0.5f * (x[1] + x[3]);
    cp[8] = 0.5f * (x[2] + x[6]);
    cp[9] = 0.5f * (x[5] + x[7]);
  }
  __syncthreads();
  if (node < N) {
    const float* W0 = Wt;
    const float* W1 = Wt + C * C;
    const float* W2 = Wt + 2 * C * C;
    float o[10];
#pragma unroll
    for (int j = 0; j < 10; j++) o[j] = 0.f;
    for (int k = 0; k < C; k++) {
      const float w0 = W0[k * C + c];
      const float w1 = W1[k * C + c];
      const float w2 = W2[k * C + c];
      const float* cp = comps[ln][k];
      o[0] += cp[0] * w0;
      o[1] += cp[1] * w1; o[2] += cp[2] * w1; o[3] += cp[3] * w1;
      o[4] += cp[4] * w2; o[5] += cp[5] * w2; o[6] += cp[6] * w2;
      o[7] += cp[7] * w2; o[8] += cp[8] * w2; o[9] += cp[9] * w2;
    }
    float* np_ = nf + ((size_t)node * C + c) * 10;
#pragma unroll
    for (int j = 0; j < 10; j++) np_[j] = o[j];
  }
}

// ---------------------------------------------------------------------------
// CSR build: histogram by src, single-block scan, fill edge list.
// ---------------------------------------------------------------------------
__global__ __launch_bounds__(256) void k_hist(const int* __restrict__ ei,
                                              int* __restrict__ deg, int E) {
  int e = blockIdx.x * 256 + threadIdx.x;
  if (e < E) atomicAdd(&deg[ei[e]], 1);
}

__global__ __launch_bounds__(1024) void k_scan(const int* __restrict__ deg,
                                               int* __restrict__ off, int N) {
  __shared__ int sums[1024];
  const int t = threadIdx.x;
  const int L = (N + 1023) / 1024;
  const int base = t * L;
  int s = 0;
  for (int j = 0; j < L; j++) if (base + j < N) s += deg[base + j];
  sums[t] = s;
  __syncthreads();
  for (int d = 1; d < 1024; d <<= 1) {
    int v = (t >= d) ? sums[t - d] : 0;
    __syncthreads();
    sums[t] += v;
    __syncthreads();
  }
  int run = (t > 0) ? sums[t - 1] : 0;
  for (int j = 0; j < L; j++) {
    if (base + j < N) { off[base + j] = run; run += deg[base + j]; }
  }
  if (t == 1023) off[N] = sums[1023];
}

__global__ __launch_bounds__(256) void k_fill(const int* __restrict__ ei,
                                              const int* __restrict__ off,
                                              int* __restrict__ cur,
                                              int* __restrict__ elist, int E) {
  int e = blockIdx.x * 256 + threadIdx.x;
  if (e < E) {
    int s = ei[e];
    int pos = off[s] + atomicAdd(&cur[s], 1);
    elist[pos] = e;
  }
}

// ---------------------------------------------------------------------------
// Edge MLP -> fa[E][192] (silu(h3) * cosine cutoff, flat h3 order).
// 64 edges/block, 256 threads. Transposed LDS activations [k][e] so the
// inner-loop reads are wave-broadcast float4s; weights stream coalesced.
// ---------------------------------------------------------------------------
#define LD16(ARR, K, B) { const float4* _p = reinterpret_cast<const float4*>(&ARR[K][B]); \
                          q0 = _p[0]; q1 = _p[1]; q2 = _p[2]; q3 = _p[3]; }
#define FMA16(ACC, W) { ACC[0] += (W)*q0.x; ACC[1] += (W)*q0.y; ACC[2] += (W)*q0.z; ACC[3] += (W)*q0.w; \
                        ACC[4] += (W)*q1.x; ACC[5] += (W)*q1.y; ACC[6] += (W)*q1.z; ACC[7] += (W)*q1.w; \
                        ACC[8] += (W)*q2.x; ACC[9] += (W)*q2.y; ACC[10] += (W)*q2.z; ACC[11] += (W)*q2.w; \
                        ACC[12] += (W)*q3.x; ACC[13] += (W)*q3.y; ACC[14] += (W)*q3.z; ACC[15] += (W)*q3.w; }

__global__ __launch_bounds__(256) void k_mlp(
    const float* __restrict__ ew, const float* __restrict__ ea,
    const float* __restrict__ W1, const float* __restrict__ b1,
    const float* __restrict__ W2, const float* __restrict__ b2,
    const float* __restrict__ W3, const float* __restrict__ b3,
    float* __restrict__ fa, int E) {
  __shared__ float attrT[R][64];     // [k][e]  8 KB
  __shared__ float h1T[64][64];      // [k][e] 16 KB
  __shared__ float h2T[128][64];     // [k][e] 32 KB
  __shared__ float cws[64];
  const int e0 = blockIdx.x * 64;
  const int tid = threadIdx.x;
  const int l = tid & 63;            // lane == output index within 64-group
  const int eq = tid >> 6;           // wave id == edge quarter (uniform/wave)
  const int eb = eq * 16;

  for (int i = tid; i < 64 * R; i += 256) {
    int k = i >> 6, e = i & 63;
    int ge = e0 + e;
    attrT[k][e] = (ge < E) ? ea[(size_t)ge * R + k] : 0.f;
  }
  if (tid < 64) {
    int ge = e0 + tid;
    float w = (ge < E) ? ew[ge] : 1e9f;
    float cc = 0.5f * (cosf(w * (PI_F / CUTOFF)) + 1.0f);
    cws[tid] = (w < CUTOFF) ? cc : 0.f;
  }
  __syncthreads();

  float4 q0, q1, q2, q3;
  // ---- layer 1: 32 -> 64 ----
  float a1[16];
  {
    float b = b1[l];
#pragma unroll
    for (int j = 0; j < 16; j++) a1[j] = b;
  }
  for (int k = 0; k < R; k++) {
    float w = W1[k * 64 + l];
    LD16(attrT, k, eb);
    FMA16(a1, w);
  }
  {
    float4* hp = reinterpret_cast<float4*>(&h1T[l][eb]);
    float t[16];
#pragma unroll
    for (int j = 0; j < 16; j++) t[j] = silu(a1[j]);
    hp[0] = make_float4(t[0], t[1], t[2], t[3]);
    hp[1] = make_float4(t[4], t[5], t[6], t[7]);
    hp[2] = make_float4(t[8], t[9], t[10], t[11]);
    hp[3] = make_float4(t[12], t[13], t[14], t[15]);
  }
  __syncthreads();

  // ---- layer 2: 64 -> 128 (outputs l and l+64) ----
  float a2A[16], a2B[16];
  {
    float bA = b2[l], bB = b2[64 + l];
#pragma unroll
    for (int j = 0; j < 16; j++) { a2A[j] = bA; a2B[j] = bB; }
  }
#pragma unroll 2
  for (int k = 0; k < 64; k++) {
    float wA = W2[k * 128 + l];
    float wB = W2[k * 128 + 64 + l];
    LD16(h1T, k, eb);
    FMA16(a2A, wA);
    FMA16(a2B, wB);
  }
  {
    float4* hpA = reinterpret_cast<float4*>(&h2T[l][eb]);
    float4* hpB = reinterpret_cast<float4*>(&h2T[64 + l][eb]);
    float tA[16], tB[16];
#pragma unroll
    for (int j = 0; j < 16; j++) { tA[j] = silu(a2A[j]); tB[j] = silu(a2B[j]); }
    hpA[0] = make_float4(tA[0], tA[1], tA[2], tA[3]);
    hpA[1] = make_float4(tA[4], tA[5], tA[6], tA[7]);
    hpA[2] = make_float4(tA[8], tA[9], tA[10], tA[11]);
    hpA[3] = make_float4(tA[12], tA[13], tA[14], tA[15]);
    hpB[0] = make_float4(tB[0], tB[1], tB[2], tB[3]);
    hpB[1] = make_float4(tB[4], tB[5], tB[6], tB[7]);
    hpB[2] = make_float4(tB[8], tB[9], tB[10], tB[11]);
    hpB[3] = make_float4(tB[12], tB[13], tB[14], tB[15]);
  }
  __syncthreads();

  // ---- layer 3: 128 -> 192 (outputs l, l+64, l+128) ----
  float a3A[16], a3B[16], a3C[16];
  {
    float bA = b3[l], bB = b3[64 + l], bC = b3[128 + l];
#pragma unroll
    for (int j = 0; j < 16; j++) { a3A[j] = bA; a3B[j] = bB; a3C[j] = bC; }
  }
#pragma unroll 2
  for (int k = 0; k < 128; k++) {
    float wA = W3[k * 192 + l];
    float wB = W3[k * 192 + 64 + l];
    float wC = W3[k * 192 + 128 + l];
    LD16(h2T, k, eb);
    FMA16(a3A, wA);
    FMA16(a3B, wB);
    FMA16(a3C, wC);
  }
#pragma unroll
  for (int j = 0; j < 16; j++) {
    int e = eb + j;
    int ge = e0 + e;
    if (ge < E) {
      float cwv = cws[e];
      float* fp = fa + (size_t)ge * 192;
      fp[l]       = silu(a3A[j]) * cwv;
      fp[64 + l]  = silu(a3B[j]) * cwv;
      fp[128 + l] = silu(a3C[j]) * cwv;
    }
  }
}

// ---------------------------------------------------------------------------
// Fused gather + output. One wave per node (lane = channel). Accumulate msg
// in registers over the node's CSR edge list, then M = GY+YG, decompose,
// mix with Wt[3..5], out = Xn + dX + dX^2.
// ---------------------------------------------------------------------------
__global__ __launch_bounds__(256) void k_gather_out(
    const int* __restrict__ ei, const int* __restrict__ off,
    const int* __restrict__ elist, const float* __restrict__ fa,
    const float* __restrict__ nf, const float* __restrict__ Xn,
    const float* __restrict__ Wt, float* __restrict__ out, int N, int E) {
  const int ln = threadIdx.x >> 6;
  const int c  = threadIdx.x & 63;
  const int node = blockIdx.x * 4 + ln;
  __shared__ float comps[4][C][10];

  float m[9];
#pragma unroll
  for (int j = 0; j < 9; j++) m[j] = 0.f;

  if (node < N) {
    const int s = off[node], t = off[node + 1];
    for (int idx = s; idx < t; idx++) {
      int e = elist[idx];
      int dst = ei[E + e];
      const float* fp = fa + (size_t)e * 192 + 3 * c;
      float f0 = fp[0], f1 = fp[1], f2 = fp[2];
      const float* p = nf + ((size_t)dst * C + c) * 10;
      float iv = p[0], a0 = p[1], a1 = p[2], a2 = p[3];
      float s00 = p[4], s11 = p[5], s22 = p[6], s01 = p[7], s02 = p[8], s12 = p[9];
      float d0 = f0 * iv;
      m[0] += d0 + f2 * s00; m[4] += d0 + f2 * s11; m[8] += d0 + f2 * s22;
      float A01 = f1 * a0, A02 = f1 * a1, A12 = f1 * a2;
      float S01 = f2 * s01, S02 = f2 * s02, S12 = f2 * s12;
      m[1] += A01 + S01; m[3] += S01 - A01;
      m[2] += A02 + S02; m[6] += S02 - A02;
      m[5] += A12 + S12; m[7] += S12 - A12;
    }
    // Y from this node's compressed features
    const float* p = nf + ((size_t)node * C + c) * 10;
    float iv = p[0], a0 = p[1], a1 = p[2], a2 = p[3];
    float s00 = p[4], s11 = p[5], s22 = p[6], s01 = p[7], s02 = p[8], s12 = p[9];
    float Y[9] = { iv + s00, a0 + s01, a1 + s02,
                   s01 - a0, iv + s11, a2 + s12,
                   s02 - a1, s12 - a2, iv + s22 };
    float M[9];
#pragma unroll
    for (int i2 = 0; i2 < 3; i2++)
#pragma unroll
      for (int j2 = 0; j2 < 3; j2++) {
        float acc = 0.f;
#pragma unroll
        for (int k2 = 0; k2 < 3; k2++)
          acc += m[i2 * 3 + k2] * Y[k2 * 3 + j2] + Y[i2 * 3 + k2] * m[k2 * 3 + j2];
        M[i2 * 3 + j2] = acc;
      }
    float nrm = 0.f;
#pragma unroll
    for (int j = 0; j < 9; j++) nrm += M[j] * M[j];
    const float inv = 1.0f / (nrm + 1.0f);
    const float tr3 = (M[0] + M[4] + M[8]) * (1.f / 3.f);
    float* cp = comps[ln][c];
    cp[0] = tr3 * inv;
    cp[1] = 0.5f * (M[1] - M[3]) * inv;
    cp[2] = 0.5f * (M[2] - M[6]) * inv;
    cp[3] = 0.5f * (M[5] - M[7]) * inv;
    cp[4] = (M[0] - tr3) * inv;
    cp[5] = (M[4] - tr3) * inv;
    cp[6] = (M[8] - tr3) * inv;
    cp[7] = 0.5f * (M[1] + M[3]) * inv;
    cp[8] = 0.5f * (M[2] + M[6]) * inv;
    cp[9] = 0.5f * (M[5] + M[7]) * inv;
  }
  __syncthreads();
  if (node < N) {
    const float* W3p = Wt + 3 * C * C;
    const float* W4p = Wt + 4 * C * C;
    const float* W5p = Wt + 5 * C * C;
    float o[10];
#pragma unroll
    for (int j = 0; j < 10; j++) o[j] = 0.f;
    for (int k = 0; k < C; k++) {
      const float w3 = W3p[k * C + c];
      const float w4 = W4p[k * C + c];
      const float w5 = W5p[k * C + c];
      const float* cp = comps[ln][k];
      o[0] += cp[0] * w3;
      o[1] += cp[1] * w4; o[2] += cp[2] * w4; o[3] += cp[3] * w4;
      o[4] += cp[4] * w5; o[5] += cp[5] * w5; o[6] += cp[6] * w5;
      o[7] += cp[7] * w5; o[8] += cp[8] * w5; o[9] += cp[9] * w5;
    }
    float dX[9] = { o[0] + o[4], o[1] + o[7], o[2] + o[8],
                    o[7] - o[1], o[0] + o[5], o[3] + o[9],
                    o[8] - o[2], o[9] - o[3], o[0] + o[6] };
    float dd[9];
#pragma unroll
    for (int i2 = 0; i2 < 3; i2++)
#pragma unroll
      for (int j2 = 0; j2 < 3; j2++) {
        float acc = 0.f;
#pragma unroll
        for (int k2 = 0; k2 < 3; k2++) acc += dX[i2 * 3 + k2] * dX[k2 * 3 + j2];
        dd[i2 * 3 + j2] = acc;
      }
    const float* xnp = Xn + ((size_t)node * C + c) * 9;
    float* op = out + ((size_t)node * C + c) * 9;
#pragma unroll
    for (int j = 0; j < 9; j++) op[j] = xnp[j] + dX[j] + dd[j];
  }
}

// ---------------------------------------------------------------------------
// Fallback (small ws): round-1 atomic scatter path.
// ---------------------------------------------------------------------------
__global__ __launch_bounds__(256) void k_edge_atomic(
    const int* __restrict__ ei, const float* __restrict__ ew,
    const float* __restrict__ ea,
    const float* __restrict__ W1, const float* __restrict__ b1,
    const float* __restrict__ W2, const float* __restrict__ b2,
    const float* __restrict__ W3, const float* __restrict__ b3,
    const float* __restrict__ nf, float* __restrict__ msg, int E) {
  __shared__ float attr[32][R];
  __shared__ float h1[32][C];
  __shared__ float h2[32][2 * C];
  __shared__ float h3[32][3 * C];
  __shared__ float cw[32];
  const int e0 = blockIdx.x * 32;
  const int tid = threadIdx.x;

  for (int i = tid; i < 32 * R; i += 256) {
    int e = i / R, k = i % R;
    int ge = e0 + e;
    attr[e][k] = (ge < E) ? ea[(size_t)ge * R + k] : 0.f;
  }
  if (tid < 32) {
    int ge = e0 + tid;
    float w = (ge < E) ? ew[ge] : 0.f;
    float cc = 0.5f * (cosf(w * (PI_F / CUTOFF)) + 1.0f);
    cw[tid] = (w < CUTOFF) ? cc : 0.f;
  }
  __syncthreads();
  for (int i = tid; i < 32 * C; i += 256) {
    int e = i / C, l = i % C;
    float acc = b1[l];
    for (int k = 0; k < R; k++) acc += attr[e][k] * W1[k * C + l];
    h1[e][l] = silu(acc);
  }
  __syncthreads();
  for (int i = tid; i < 32 * 2 * C; i += 256) {
    int e = i / (2 * C), l = i % (2 * C);
    float acc = b2[l];
    for (int k = 0; k < C; k++) acc += h1[e][k] * W2[k * 2 * C + l];
    h2[e][l] = silu(acc);
  }
  __syncthreads();
  for (int i = tid; i < 32 * 3 * C; i += 256) {
    int e = i / (3 * C), l = i % (3 * C);
    float acc = b3[l];
    for (int k = 0; k < 2 * C; k++) acc += h2[e][k] * W3[k * 3 * C + l];
    h3[e][l] = silu(acc);
  }
  __syncthreads();
  for (int i = tid; i < 32 * C; i += 256) {
    int e = i / C, c = i % C;
    int ge = e0 + e;
    if (ge >= E) continue;
    int src = ei[ge];
    int dst = ei[E + ge];
    float cwv = cw[e];
    float f0 = h3[e][3 * c + 0] * cwv;
    float f1 = h3[e][3 * c + 1] * cwv;
    float f2 = h3[e][3 * c + 2] * cwv;
    const float* p = nf + ((size_t)dst * C + c) * 10;
    float iv = p[0], a0 = p[1], a1 = p[2], a2 = p[3];
    float s00 = p[4], s11 = p[5], s22 = p[6], s01 = p[7], s02 = p[8], s12 = p[9];
    float d0 = f0 * iv;
    float A01 = f1 * a0, A02 = f1 * a1, A12 = f1 * a2;
    float S01 = f2 * s01, S02 = f2 * s02, S12 = f2 * s12;
    float mv[9];
    mv[0] = d0 + f2 * s00; mv[4] = d0 + f2 * s11; mv[8] = d0 + f2 * s22;
    mv[1] = A01 + S01; mv[3] = S01 - A01;
    mv[2] = A02 + S02; mv[6] = S02 - A02;
    mv[5] = A12 + S12; mv[7] = S12 - A12;
    float* mp_ = msg + ((size_t)src * C + c) * 9;
#pragma unroll
    for (int j = 0; j < 9; j++) atomicAdd(mp_ + j, mv[j]);
  }
}

__global__ __launch_bounds__(256) void k_out_sep(
    const float* __restrict__ msg, const float* __restrict__ nf,
    const float* __restrict__ Xn, const float* __restrict__ Wt,
    float* __restrict__ out, int N) {
  const int ln = threadIdx.x >> 6;
  const int c  = threadIdx.x & 63;
  const int node = blockIdx.x * 4 + ln;
  __shared__ float comps[4][C][10];
  if (node < N) {
    const float* p = nf + ((size_t)node * C + c) * 10;
    float iv = p[0], a0 = p[1], a1 = p[2], a2 = p[3];
    float s00 = p[4], s11 = p[5], s22 = p[6], s01 = p[7], s02 = p[8], s12 = p[9];
    float Y[9] = { iv + s00, a0 + s01, a1 + s02,
                   s01 - a0, iv + s11, a2 + s12,
                   s02 - a1, s12 - a2, iv + s22 };
    const float* mq = msg + ((size_t)node * C + c) * 9;
    float G[9];
#pragma unroll
    for (int j = 0; j < 9; j++) G[j] = mq[j];
    float M[9];
#pragma unroll
    for (int i2 = 0; i2 < 3; i2++)
#pragma unroll
      for (int j2 = 0; j2 < 3; j2++) {
        float acc = 0.f;
#pragma unroll
        for (int k2 = 0; k2 < 3; k2++)
          acc += G[i2 * 3 + k2] * Y[k2 * 3 + j2] + Y[i2 * 3 + k2] * G[k2 * 3 + j2];
        M[i2 * 3 + j2] = acc;
      }
    float nrm = 0.f;
#pragma unroll
    for (int j = 0; j < 9; j++) nrm += M[j] * M[j];
    const float inv = 1.0f / (nrm + 1.0f);
    const float tr3 = (M[0] + M[4] + M[8]) * (1.f / 3.f);
    float* cp = comps[ln][c];
    cp[0] = tr3 * inv;
    cp[1] = 0.5f * (M[1] - M[3]) * inv;
    cp[2] = 0.5f * (M[2] - M[6]) * inv;
    cp[3] = 0.5f * (M[5] - M[7]) * inv;
    cp[4] = (M[0] - tr3) * inv;
    cp[5] = (M[4] - tr3) * inv;
    cp[6] = (M[8] - tr3) * inv;
    cp[7] = 0.5f * (M[1] + M[3]) * inv;
    cp[8] = 0.5f * (M[2] + M[6]) * inv;
    cp[9] = 0.5f * (M[5] + M[7]) * inv;
  }
  __syncthreads();
  if (node < N) {
    const float* W3p = Wt + 3 * C * C;
    const float* W4p = Wt + 4 * C * C;
    const float* W5p = Wt + 5 * C * C;
    float o[10];
#pragma unroll
    for (int j = 0; j < 10; j++) o[j] = 0.f;
    for (int k = 0; k < C; k++) {
      const float w3 = W3p[k * C + c];
      const float w4 = W4p[k * C + c];
      const float w5 = W5p[k * C + c];
      const float* cp = comps[ln][k];
      o[0] += cp[0] * w3;
      o[1] += cp[1] * w4; o[2] += cp[2] * w4; o[3] += cp[3] * w4;
      o[4] += cp[4] * w5; o[5] += cp[5] * w5; o[6] += cp[6] * w5;
      o[7] += cp[7] * w5; o[8] += cp[8] * w5; o[9] += cp[9] * w5;
    }
    float dX[9] = { o[0] + o[4], o[1] + o[7], o[2] + o[8],
                    o[7] - o[1], o[0] + o[5], o[3] + o[9],
                    o[8] - o[2], o[9] - o[3], o[0] + o[6] };
    float dd[9];
#pragma unroll
    for (int i2 = 0; i2 < 3; i2++)
#pragma unroll
      for (int j2 = 0; j2 < 3; j2++) {
        float acc = 0.f;
#pragma unroll
        for (int k2 = 0; k2 < 3; k2++) acc += dX[i2 * 3 + k2] * dX[k2 * 3 + j2];
        dd[i2 * 3 + j2] = acc;
      }
    const float* xnp = Xn + ((size_t)node * C + c) * 9;
    float* op = out + ((size_t)node * C + c) * 9;
#pragma unroll
    for (int j = 0; j < 9; j++) op[j] = xnp[j] + dX[j] + dd[j];
  }
}

extern "C" void kernel_launch(void* const* d_in, const int* in_sizes, int n_in,
                              void* d_out, int out_size, void* d_ws, size_t ws_size,
                              hipStream_t stream) {
  const float* X  = (const float*)d_in[0];
  const int*   ei = (const int*)d_in[1];
  const float* ew = (const float*)d_in[2];
  const float* ea = (const float*)d_in[3];
  const float* W1 = (const float*)d_in[4];
  const float* b1 = (const float*)d_in[5];
  const float* W2 = (const float*)d_in[6];
  const float* b2 = (const float*)d_in[7];
  const float* W3 = (const float*)d_in[8];
  const float* b3 = (const float*)d_in[9];
  const float* Wt = (const float*)d_in[10];
  const int N = in_sizes[0] / (C * 9);
  const int E = in_sizes[1] / 2;

  float* nf = (float*)d_ws;                         // [N][C][10]
  float* Xn = nf + (size_t)N * C * 10;              // [N][C][9]
  float* fa = Xn + (size_t)N * C * 9;               // [E][192]
  int* deg  = (int*)(fa + (size_t)E * 192);         // [N]
  int* off  = deg + N;                              // [N+1]
  int* cur  = off + N + 1;                          // [N]
  int* elist = cur + N;                             // [E]
  size_t need = (size_t)((char*)(elist + E) - (char*)d_ws);

  k_node_prep<<<(N + 3) / 4, 256, 0, stream>>>(X, Wt, Xn, nf, N);

  if (ws_size >= need) {
    hipMemsetAsync(deg, 0, (size_t)N * sizeof(int), stream);
    hipMemsetAsync(cur, 0, (size_t)N * sizeof(int), stream);
    k_hist<<<(E + 255) / 256, 256, 0, stream>>>(ei, deg, E);
    k_scan<<<1, 1024, 0, stream>>>(deg, off, N);
    k_fill<<<(E + 255) / 256, 256, 0, stream>>>(ei, off, cur, elist, E);
    k_mlp<<<(E + 63) / 64, 256, 0, stream>>>(ew, ea, W1, b1, W2, b2, W3, b3, fa, E);
    k_gather_out<<<(N + 3) / 4, 256, 0, stream>>>(ei, off, elist, fa, nf, Xn, Wt,
                                                  (float*)d_out, N, E);
  } else {
    float* msg = fa;                                // [N][C][9] fallback
    hipMemsetAsync(msg, 0, (size_t)N * C * 9 * sizeof(float), stream);
    k_edge_atomic<<<(E + 31) / 32, 256, 0, stream>>>(ei, ew, ea, W1, b1, W2, b2,
                                                     W3, b3, nf, msg, E);
    k_out_sep<<<(N + 3) / 4, 256, 0, stream>>>(msg, nf, Xn, Wt, (float*)d_out, N);
  }
}

// Round 3
// 240.093 us; speedup vs baseline: 12.9777x; 1.5334x over previous
//
#include <hip/hip_runtime.h>
#include <math.h>

#define C 64
#define R 32
#define CUTOFF 5.0f
#define PI_F 3.14159265358979323846f

typedef __attribute__((ext_vector_type(8))) short short8b;
typedef __attribute__((ext_vector_type(4))) short short4b;
typedef __attribute__((ext_vector_type(4))) float f32x4;

__device__ __forceinline__ float silu(float x) { return x / (1.0f + __expf(-x)); }

__device__ __forceinline__ unsigned short f2bfu(float x) {
  unsigned u = __builtin_bit_cast(unsigned, x);
  u += 0x7FFF + ((u >> 16) & 1);           // round-to-nearest-even
  return (unsigned short)(u >> 16);
}
__device__ __forceinline__ float bfu2f(unsigned short s) {
  return __builtin_bit_cast(float, (unsigned)s << 16);
}

// ---------------------------------------------------------------------------
// Weight prep: permute W1/W2/W3 (fp32, row-major [k][n]) into bf16 MFMA
// B-fragments: Wf[(kstep*ntiles + ntile)*64 + lane][8].
// k(l,i) = ks*32 + (l>>4)*4 + (i&3) + 16*(i>>2);  n(l) = nt*16 + (l&15).
// Layout: L1 @ u16[0..2048), L2 @ [2048..10240), L3 @ [10240..34816).
// ---------------------------------------------------------------------------
__global__ __launch_bounds__(256) void k_wprep(
    const float* __restrict__ W1, const float* __restrict__ W2,
    const float* __restrict__ W3, unsigned short* __restrict__ Wf) {
  int id = blockIdx.x * 256 + threadIdx.x;
  if (id >= 34816) return;
  const float* W; int ntiles, Nout, id2;
  if (id < 2048)       { W = W1; ntiles = 4;  Nout = 64;  id2 = id; }
  else if (id < 10240) { W = W2; ntiles = 8;  Nout = 128; id2 = id - 2048; }
  else                 { W = W3; ntiles = 12; Nout = 192; id2 = id - 10240; }
  int i = id2 & 7;
  int l = (id2 >> 3) & 63;
  int t = id2 >> 9;                 // ks*ntiles + nt
  int nt = t % ntiles, ks = t / ntiles;
  int k = ks * 32 + ((l >> 4) << 2) + (i & 3) + ((i >> 2) << 4);
  int n = nt * 16 + (l & 15);
  Wf[id] = f2bfu(W[(size_t)k * Nout + n]);
}

// ---------------------------------------------------------------------------
// Node prep: Xn = X/(||X||^2+1); decompose -> 10 comps; mix with Wt[0..2].
// Outputs transposed: Xn[N][9][C], nf[N][10][C] (coalesced gather reads).
// Block = 4 nodes x 64 channels.
// ---------------------------------------------------------------------------
__global__ __launch_bounds__(256) void k_node_prep(
    const float* __restrict__ X, const float* __restrict__ Wt,
    float* __restrict__ Xn, float* __restrict__ nf, int N) {
  const int ln = threadIdx.x >> 6;
  const int c  = threadIdx.x & 63;
  const int node = blockIdx.x * 4 + ln;
  __shared__ float comps[4][C][12];   // padded to 12 for float4 reads

  if (node < N) {
    const float* xp = X + ((size_t)node * C + c) * 9;
    float x[9]; float nrm = 0.f;
#pragma unroll
    for (int j = 0; j < 9; j++) { x[j] = xp[j]; nrm += x[j] * x[j]; }
    const float inv = 1.0f / (nrm + 1.0f);
#pragma unroll
    for (int j = 0; j < 9; j++) x[j] *= inv;
    float* xnp = Xn + (size_t)node * 576 + c;
#pragma unroll
    for (int j = 0; j < 9; j++) xnp[j * 64] = x[j];
    const float tr3 = (x[0] + x[4] + x[8]) * (1.f / 3.f);
    float* cp = comps[ln][c];
    cp[0] = tr3;
    cp[1] = 0.5f * (x[1] - x[3]);
    cp[2] = 0.5f * (x[2] - x[6]);
    cp[3] = 0.5f * (x[5] - x[7]);
    cp[4] = x[0] - tr3;
    cp[5] = x[4] - tr3;
    cp[6] = x[8] - tr3;
    cp[7] = 0.5f * (x[1] + x[3]);
    cp[8] = 0.5f * (x[2] + x[6]);
    cp[9] = 0.5f * (x[5] + x[7]);
  }
  __syncthreads();
  if (node < N) {
    const float* W0 = Wt;
    const float* W1 = Wt + C * C;
    const float* W2 = Wt + 2 * C * C;
    float o[10];
#pragma unroll
    for (int j = 0; j < 10; j++) o[j] = 0.f;
    for (int k = 0; k < C; k++) {
      const float w0 = W0[k * C + c];
      const float w1 = W1[k * C + c];
      const float w2 = W2[k * C + c];
      const float4* cq = (const float4*)comps[ln][k];
      float4 q0 = cq[0], q1 = cq[1];
      float2 q2 = *(const float2*)(comps[ln][k] + 8);
      o[0] += q0.x * w0;
      o[1] += q0.y * w1; o[2] += q0.z * w1; o[3] += q0.w * w1;
      o[4] += q1.x * w2; o[5] += q1.y * w2; o[6] += q1.z * w2;
      o[7] += q1.w * w2; o[8] += q2.x * w2; o[9] += q2.y * w2;
    }
    float* np_ = nf + (size_t)node * 640 + c;
#pragma unroll
    for (int j = 0; j < 10; j++) np_[j * 64] = o[j];
  }
}

// ---------------------------------------------------------------------------
// CSR build: histogram by src, single-block scan, fill edge list.
// ---------------------------------------------------------------------------
__global__ __launch_bounds__(256) void k_hist(const int* __restrict__ ei,
                                              int* __restrict__ deg, int E) {
  int e = blockIdx.x * 256 + threadIdx.x;
  if (e < E) atomicAdd(&deg[ei[e]], 1);
}

__global__ __launch_bounds__(1024) void k_scan(const int* __restrict__ deg,
                                               int* __restrict__ off, int N) {
  __shared__ int sums[1024];
  const int t = threadIdx.x;
  const int L = (N + 1023) / 1024;
  const int base = t * L;
  int s = 0;
  for (int j = 0; j < L; j++) if (base + j < N) s += deg[base + j];
  sums[t] = s;
  __syncthreads();
  for (int d = 1; d < 1024; d <<= 1) {
    int v = (t >= d) ? sums[t - d] : 0;
    __syncthreads();
    sums[t] += v;
    __syncthreads();
  }
  int run = (t > 0) ? sums[t - 1] : 0;
  for (int j = 0; j < L; j++) {
    if (base + j < N) { off[base + j] = run; run += deg[base + j]; }
  }
  if (t == 1023) off[N] = sums[1023];
}

__global__ __launch_bounds__(256) void k_fill(const int* __restrict__ ei,
                                              const int* __restrict__ off,
                                              int* __restrict__ cur,
                                              int* __restrict__ elist, int E) {
  int e = blockIdx.x * 256 + threadIdx.x;
  if (e < E) {
    int s = ei[e];
    int pos = off[s] + atomicAdd(&cur[s], 1);
    elist[pos] = e;
  }
}

// ---------------------------------------------------------------------------
// Edge MLP via MFMA bf16 (fp32 accum). Block = 64 edges, 4 waves; wave w owns
// edge rows 16w..16w+15 across all layers. Activations staged in padded bf16
// LDS. Output fa[E][3][64] bf16 = silu(h3)*cw, permuted (n -> [n%3][n/3]).
// ---------------------------------------------------------------------------
__global__ __launch_bounds__(256) void k_mlp(
    const float* __restrict__ ew, const float* __restrict__ ea,
    const float* __restrict__ b1, const float* __restrict__ b2,
    const float* __restrict__ b3, const unsigned short* __restrict__ Wf,
    unsigned short* __restrict__ fa, int E) {
  __shared__ unsigned short attrB[64][40];   // rows 80 B (use 32)
  __shared__ unsigned short h1B[64][72];     // rows 144 B (use 64)
  __shared__ unsigned short h2B[64][136];    // rows 272 B (use 128)
  __shared__ float cws[64];
  const int e0 = blockIdx.x * 64;
  const int tid = threadIdx.x;

  { // stage edge_attr -> bf16 LDS (4 threads/edge, 8 floats each)
    int e = tid >> 2, q = tid & 3;
    int ge = e0 + e;
    uint4 pk;
    if (ge < E) {
      const float4* p = (const float4*)(ea + (size_t)ge * R + q * 8);
      float4 x0 = p[0], x1 = p[1];
      pk.x = (unsigned)f2bfu(x0.x) | ((unsigned)f2bfu(x0.y) << 16);
      pk.y = (unsigned)f2bfu(x0.z) | ((unsigned)f2bfu(x0.w) << 16);
      pk.z = (unsigned)f2bfu(x1.x) | ((unsigned)f2bfu(x1.y) << 16);
      pk.w = (unsigned)f2bfu(x1.z) | ((unsigned)f2bfu(x1.w) << 16);
    } else {
      pk = make_uint4(0, 0, 0, 0);
    }
    *(uint4*)&attrB[e][q * 8] = pk;
  }
  if (tid < 64) {
    int ge = e0 + tid;
    float wgt = (ge < E) ? ew[ge] : 1e9f;
    float cc = 0.5f * (cosf(wgt * (PI_F / CUTOFF)) + 1.0f);
    cws[tid] = (wgt < CUTOFF) ? cc : 0.f;
  }
  __syncthreads();

  const int l = tid & 63, wv = tid >> 6;
  const int g = l >> 4, r = l & 15;
  const int mrow = 16 * wv + r;

  const short8b* WfL1 = (const short8b*)Wf;
  const short8b* WfL2 = WfL1 + 256;
  const short8b* WfL3 = WfL1 + 1280;

  // ---- layer 1: 32 -> 64, K=32 (1 step) ----
  f32x4 acc1[4];
#pragma unroll
  for (int nt = 0; nt < 4; nt++) {
    float b = b1[nt * 16 + r];
    acc1[nt] = (f32x4){b, b, b, b};
  }
  {
    const unsigned short* arow = &attrB[mrow][0];
    short4b lo = *(const short4b*)(arow + g * 4);
    short4b hi = *(const short4b*)(arow + 16 + g * 4);
    short8b a = __builtin_shufflevector(lo, hi, 0, 1, 2, 3, 4, 5, 6, 7);
#pragma unroll
    for (int nt = 0; nt < 4; nt++)
      acc1[nt] = __builtin_amdgcn_mfma_f32_16x16x32_bf16(a, WfL1[nt * 64 + l], acc1[nt], 0, 0, 0);
  }
#pragma unroll
  for (int nt = 0; nt < 4; nt++)
#pragma unroll
    for (int reg = 0; reg < 4; reg++)
      h1B[16 * wv + g * 4 + reg][nt * 16 + r] = f2bfu(silu(acc1[nt][reg]));
  __syncthreads();

  // ---- layer 2: 64 -> 128, K=64 (2 steps) ----
  f32x4 acc2[8];
#pragma unroll
  for (int nt = 0; nt < 8; nt++) {
    float b = b2[nt * 16 + r];
    acc2[nt] = (f32x4){b, b, b, b};
  }
#pragma unroll
  for (int s = 0; s < 2; s++) {
    const unsigned short* hrow = &h1B[mrow][s * 32];
    short4b lo = *(const short4b*)(hrow + g * 4);
    short4b hi = *(const short4b*)(hrow + 16 + g * 4);
    short8b a = __builtin_shufflevector(lo, hi, 0, 1, 2, 3, 4, 5, 6, 7);
#pragma unroll
    for (int nt = 0; nt < 8; nt++)
      acc2[nt] = __builtin_amdgcn_mfma_f32_16x16x32_bf16(a, WfL2[(s * 8 + nt) * 64 + l], acc2[nt], 0, 0, 0);
  }
#pragma unroll
  for (int nt = 0; nt < 8; nt++)
#pragma unroll
    for (int reg = 0; reg < 4; reg++)
      h2B[16 * wv + g * 4 + reg][nt * 16 + r] = f2bfu(silu(acc2[nt][reg]));
  __syncthreads();

  // ---- layer 3: 128 -> 192, K=128 (4 steps) ----
  f32x4 acc3[12];
#pragma unroll
  for (int nt = 0; nt < 12; nt++) {
    float b = b3[nt * 16 + r];
    acc3[nt] = (f32x4){b, b, b, b};
  }
#pragma unroll
  for (int s = 0; s < 4; s++) {
    const unsigned short* hrow = &h2B[mrow][s * 32];
    short4b lo = *(const short4b*)(hrow + g * 4);
    short4b hi = *(const short4b*)(hrow + 16 + g * 4);
    short8b a = __builtin_shufflevector(lo, hi, 0, 1, 2, 3, 4, 5, 6, 7);
#pragma unroll
    for (int nt = 0; nt < 12; nt++)
      acc3[nt] = __builtin_amdgcn_mfma_f32_16x16x32_bf16(a, WfL3[(s * 12 + nt) * 64 + l], acc3[nt], 0, 0, 0);
  }

  float cwr[4];
#pragma unroll
  for (int reg = 0; reg < 4; reg++) cwr[reg] = cws[16 * wv + g * 4 + reg];
#pragma unroll
  for (int nt = 0; nt < 12; nt++) {
    int n = nt * 16 + r;
    int ch = n / 3;
    int j3 = n - ch * 3;
#pragma unroll
    for (int reg = 0; reg < 4; reg++) {
      int row = 16 * wv + g * 4 + reg;
      int ge = e0 + row;
      if (ge < E) {
        float v = silu(acc3[nt][reg]) * cwr[reg];
        fa[(size_t)ge * 192 + j3 * 64 + ch] = f2bfu(v);
      }
    }
  }
}

// ---------------------------------------------------------------------------
// Fused gather + output. Wave per node (lane = channel). msg in registers
// over CSR edges (bf16 fa, transposed nf), then M = GY+YG, decompose,
// mix with Wt[3..5], out = Xn + dX + dX^2.
// ---------------------------------------------------------------------------
__global__ __launch_bounds__(256) void k_gather_out(
    const int* __restrict__ ei, const int* __restrict__ off,
    const int* __restrict__ elist, const unsigned short* __restrict__ fa,
    const float* __restrict__ nf, const float* __restrict__ Xn,
    const float* __restrict__ Wt, float* __restrict__ out, int N, int E) {
  const int ln = threadIdx.x >> 6;
  const int c  = threadIdx.x & 63;
  const int node = blockIdx.x * 4 + ln;
  __shared__ float comps[4][C][12];

  float m[9];
#pragma unroll
  for (int j = 0; j < 9; j++) m[j] = 0.f;

  if (node < N) {
    const int s = off[node], t = off[node + 1];
    for (int idx = s; idx < t; idx++) {
      int e = elist[idx];
      int dst = ei[E + e];
      const unsigned short* fp = fa + (size_t)e * 192;
      float f0 = bfu2f(fp[c]);
      float f1 = bfu2f(fp[64 + c]);
      float f2 = bfu2f(fp[128 + c]);
      const float* p = nf + (size_t)dst * 640 + c;
      float iv = p[0],   a0 = p[64],  a1 = p[128], a2 = p[192];
      float s00 = p[256], s11 = p[320], s22 = p[384];
      float s01 = p[448], s02 = p[512], s12 = p[576];
      float d0 = f0 * iv;
      m[0] += d0 + f2 * s00; m[4] += d0 + f2 * s11; m[8] += d0 + f2 * s22;
      float A01 = f1 * a0, A02 = f1 * a1, A12 = f1 * a2;
      float S01 = f2 * s01, S02 = f2 * s02, S12 = f2 * s12;
      m[1] += A01 + S01; m[3] += S01 - A01;
      m[2] += A02 + S02; m[6] += S02 - A02;
      m[5] += A12 + S12; m[7] += S12 - A12;
    }
    const float* p = nf + (size_t)node * 640 + c;
    float iv = p[0],   a0 = p[64],  a1 = p[128], a2 = p[192];
    float s00 = p[256], s11 = p[320], s22 = p[384];
    float s01 = p[448], s02 = p[512], s12 = p[576];
    float Y[9] = { iv + s00, a0 + s01, a1 + s02,
                   s01 - a0, iv + s11, a2 + s12,
                   s02 - a1, s12 - a2, iv + s22 };
    float M[9];
#pragma unroll
    for (int i2 = 0; i2 < 3; i2++)
#pragma unroll
      for (int j2 = 0; j2 < 3; j2++) {
        float acc = 0.f;
#pragma unroll
        for (int k2 = 0; k2 < 3; k2++)
          acc += m[i2 * 3 + k2] * Y[k2 * 3 + j2] + Y[i2 * 3 + k2] * m[k2 * 3 + j2];
        M[i2 * 3 + j2] = acc;
      }
    float nrm = 0.f;
#pragma unroll
    for (int j = 0; j < 9; j++) nrm += M[j] * M[j];
    const float inv = 1.0f / (nrm + 1.0f);
    const float tr3 = (M[0] + M[4] + M[8]) * (1.f / 3.f);
    float* cp = comps[ln][c];
    cp[0] = tr3 * inv;
    cp[1] = 0.5f * (M[1] - M[3]) * inv;
    cp[2] = 0.5f * (M[2] - M[6]) * inv;
    cp[3] = 0.5f * (M[5] - M[7]) * inv;
    cp[4] = (M[0] - tr3) * inv;
    cp[5] = (M[4] - tr3) * inv;
    cp[6] = (M[8] - tr3) * inv;
    cp[7] = 0.5f * (M[1] + M[3]) * inv;
    cp[8] = 0.5f * (M[2] + M[6]) * inv;
    cp[9] = 0.5f * (M[5] + M[7]) * inv;
  }
  __syncthreads();
  if (node < N) {
    const float* W3p = Wt + 3 * C * C;
    const float* W4p = Wt + 4 * C * C;
    const float* W5p = Wt + 5 * C * C;
    float o[10];
#pragma unroll
    for (int j = 0; j < 10; j++) o[j] = 0.f;
    for (int k = 0; k < C; k++) {
      const float w3 = W3p[k * C + c];
      const float w4 = W4p[k * C + c];
      const float w5 = W5p[k * C + c];
      const float4* cq = (const float4*)comps[ln][k];
      float4 q0 = cq[0], q1 = cq[1];
      float2 q2 = *(const float2*)(comps[ln][k] + 8);
      o[0] += q0.x * w3;
      o[1] += q0.y * w4; o[2] += q0.z * w4; o[3] += q0.w * w4;
      o[4] += q1.x * w5; o[5] += q1.y * w5; o[6] += q1.z * w5;
      o[7] += q1.w * w5; o[8] += q2.x * w5; o[9] += q2.y * w5;
    }
    float dX[9] = { o[0] + o[4], o[1] + o[7], o[2] + o[8],
                    o[7] - o[1], o[0] + o[5], o[3] + o[9],
                    o[8] - o[2], o[9] - o[3], o[0] + o[6] };
    float dd[9];
#pragma unroll
    for (int i2 = 0; i2 < 3; i2++)
#pragma unroll
      for (int j2 = 0; j2 < 3; j2++) {
        float acc = 0.f;
#pragma unroll
        for (int k2 = 0; k2 < 3; k2++) acc += dX[i2 * 3 + k2] * dX[k2 * 3 + j2];
        dd[i2 * 3 + j2] = acc;
      }
    const float* xnp = Xn + (size_t)node * 576 + c;
    float* op = out + ((size_t)node * C + c) * 9;
#pragma unroll
    for (int j = 0; j < 9; j++) op[j] = xnp[j * 64] + dX[j] + dd[j];
  }
}

extern "C" void kernel_launch(void* const* d_in, const int* in_sizes, int n_in,
                              void* d_out, int out_size, void* d_ws, size_t ws_size,
                              hipStream_t stream) {
  const float* X  = (const float*)d_in[0];
  const int*   ei = (const int*)d_in[1];
  const float* ew = (const float*)d_in[2];
  const float* ea = (const float*)d_in[3];
  const float* W1 = (const float*)d_in[4];
  const float* b1 = (const float*)d_in[5];
  const float* W2 = (const float*)d_in[6];
  const float* b2 = (const float*)d_in[7];
  const float* W3 = (const float*)d_in[8];
  const float* b3 = (const float*)d_in[9];
  const float* Wt = (const float*)d_in[10];
  const int N = in_sizes[0] / (C * 9);
  const int E = in_sizes[1] / 2;

  float* nf = (float*)d_ws;                                  // [N][10][C]
  float* Xn = nf + (size_t)N * 640;                          // [N][9][C]
  unsigned short* fa = (unsigned short*)(Xn + (size_t)N * 576); // [E][3][64] bf16
  unsigned short* Wf = fa + (size_t)E * 192;                 // 34816 bf16 frags
  int* deg  = (int*)(Wf + 34816);                            // [N]
  int* off  = deg + N;                                       // [N+1]
  int* cur  = off + N + 1;                                   // [N]
  int* elist = cur + N;                                      // [E]

  hipMemsetAsync(deg, 0, (size_t)N * sizeof(int), stream);
  hipMemsetAsync(cur, 0, (size_t)N * sizeof(int), stream);
  k_wprep<<<(34816 + 255) / 256, 256, 0, stream>>>(W1, W2, W3, Wf);
  k_node_prep<<<(N + 3) / 4, 256, 0, stream>>>(X, Wt, Xn, nf, N);
  k_hist<<<(E + 255) / 256, 256, 0, stream>>>(ei, deg, E);
  k_scan<<<1, 1024, 0, stream>>>(deg, off, N);
  k_fill<<<(E + 255) / 256, 256, 0, stream>>>(ei, off, cur, elist, E);
  k_mlp<<<(E + 63) / 64, 256, 0, stream>>>(ew, ea, b1, b2, b3, Wf, fa, E);
  k_gather_out<<<(N + 3) / 4, 256, 0, stream>>>(ei, off, elist, fa, nf, Xn, Wt,
                                                (float*)d_out, N, E);
}

// Round 4
// 221.988 us; speedup vs baseline: 14.0362x; 1.0816x over previous
//
#include <hip/hip_runtime.h>
#include <math.h>

#define C 64
#define R 32
#define CUTOFF 5.0f
#define PI_F 3.14159265358979323846f

typedef __attribute__((ext_vector_type(8))) short short8b;
typedef __attribute__((ext_vector_type(4))) short short4b;
typedef __attribute__((ext_vector_type(4))) float f32x4;

__device__ __forceinline__ float silu(float x) { return x / (1.0f + __expf(-x)); }

__device__ __forceinline__ unsigned short f2bfu(float x) {
  unsigned u = __builtin_bit_cast(unsigned, x);
  u += 0x7FFF + ((u >> 16) & 1);           // round-to-nearest-even
  return (unsigned short)(u >> 16);
}
__device__ __forceinline__ float bfu2f(unsigned short s) {
  return __builtin_bit_cast(float, (unsigned)s << 16);
}

// ---------------------------------------------------------------------------
// Weight prep: permute W1/W2/W3 (fp32, row-major [k][n]) into bf16 MFMA
// B-fragments: Wf[(kstep*ntiles + ntile)*64 + lane][8].
// ---------------------------------------------------------------------------
__global__ __launch_bounds__(256) void k_wprep(
    const float* __restrict__ W1, const float* __restrict__ W2,
    const float* __restrict__ W3, unsigned short* __restrict__ Wf) {
  int id = blockIdx.x * 256 + threadIdx.x;
  if (id >= 34816) return;
  const float* W; int ntiles, Nout, id2;
  if (id < 2048)       { W = W1; ntiles = 4;  Nout = 64;  id2 = id; }
  else if (id < 10240) { W = W2; ntiles = 8;  Nout = 128; id2 = id - 2048; }
  else                 { W = W3; ntiles = 12; Nout = 192; id2 = id - 10240; }
  int i = id2 & 7;
  int l = (id2 >> 3) & 63;
  int t = id2 >> 9;
  int nt = t % ntiles, ks = t / ntiles;
  int k = ks * 32 + ((l >> 4) << 2) + (i & 3) + ((i >> 2) << 4);
  int n = nt * 16 + (l & 15);
  Wf[id] = f2bfu(W[(size_t)k * Nout + n]);
}

// ---------------------------------------------------------------------------
// Node prep: Xn = X/(||X||^2+1); decompose -> 10 comps; mix with Wt[0..2].
// Outputs: Xn[N][9][C] (epilogue), nf[N][C][12] fp32 (gather, vector loads).
// ---------------------------------------------------------------------------
__global__ __launch_bounds__(256) void k_node_prep(
    const float* __restrict__ X, const float* __restrict__ Wt,
    float* __restrict__ Xn, float* __restrict__ nf, int N) {
  const int ln = threadIdx.x >> 6;
  const int c  = threadIdx.x & 63;
  const int node = blockIdx.x * 4 + ln;
  __shared__ float comps[4][C][12];

  if (node < N) {
    const float* xp = X + ((size_t)node * C + c) * 9;
    float x[9]; float nrm = 0.f;
#pragma unroll
    for (int j = 0; j < 9; j++) { x[j] = xp[j]; nrm += x[j] * x[j]; }
    const float inv = 1.0f / (nrm + 1.0f);
#pragma unroll
    for (int j = 0; j < 9; j++) x[j] *= inv;
    float* xnp = Xn + (size_t)node * 576 + c;
#pragma unroll
    for (int j = 0; j < 9; j++) xnp[j * 64] = x[j];
    const float tr3 = (x[0] + x[4] + x[8]) * (1.f / 3.f);
    float* cp = comps[ln][c];
    cp[0] = tr3;
    cp[1] = 0.5f * (x[1] - x[3]);
    cp[2] = 0.5f * (x[2] - x[6]);
    cp[3] = 0.5f * (x[5] - x[7]);
    cp[4] = x[0] - tr3;
    cp[5] = x[4] - tr3;
    cp[6] = x[8] - tr3;
    cp[7] = 0.5f * (x[1] + x[3]);
    cp[8] = 0.5f * (x[2] + x[6]);
    cp[9] = 0.5f * (x[5] + x[7]);
  }
  __syncthreads();
  if (node < N) {
    const float* W0 = Wt;
    const float* W1 = Wt + C * C;
    const float* W2 = Wt + 2 * C * C;
    float o[10];
#pragma unroll
    for (int j = 0; j < 10; j++) o[j] = 0.f;
    for (int k = 0; k < C; k++) {
      const float w0 = W0[k * C + c];
      const float w1 = W1[k * C + c];
      const float w2 = W2[k * C + c];
      const float4* cq = (const float4*)comps[ln][k];
      float4 q0 = cq[0], q1 = cq[1];
      float2 q2 = *(const float2*)(comps[ln][k] + 8);
      o[0] += q0.x * w0;
      o[1] += q0.y * w1; o[2] += q0.z * w1; o[3] += q0.w * w1;
      o[4] += q1.x * w2; o[5] += q1.y * w2; o[6] += q1.z * w2;
      o[7] += q1.w * w2; o[8] += q2.x * w2; o[9] += q2.y * w2;
    }
    float* np_ = nf + (size_t)node * 768 + c * 12;
    *(float4*)np_       = make_float4(o[0], o[1], o[2], o[3]);
    *(float4*)(np_ + 4) = make_float4(o[4], o[5], o[6], o[7]);
    *(float4*)(np_ + 8) = make_float4(o[8], o[9], 0.f, 0.f);
  }
}

// ---------------------------------------------------------------------------
// CSR build.
// ---------------------------------------------------------------------------
__global__ __launch_bounds__(256) void k_hist(const int* __restrict__ ei,
                                              int* __restrict__ deg, int E) {
  int e = blockIdx.x * 256 + threadIdx.x;
  if (e < E) atomicAdd(&deg[ei[e]], 1);
}

__global__ __launch_bounds__(1024) void k_scan(const int* __restrict__ deg,
                                               int* __restrict__ off, int N) {
  __shared__ int sums[1024];
  const int t = threadIdx.x;
  const int L = (N + 1023) / 1024;
  const int base = t * L;
  int s = 0;
  for (int j = 0; j < L; j++) if (base + j < N) s += deg[base + j];
  sums[t] = s;
  __syncthreads();
  for (int d = 1; d < 1024; d <<= 1) {
    int v = (t >= d) ? sums[t - d] : 0;
    __syncthreads();
    sums[t] += v;
    __syncthreads();
  }
  int run = (t > 0) ? sums[t - 1] : 0;
  for (int j = 0; j < L; j++) {
    if (base + j < N) { off[base + j] = run; run += deg[base + j]; }
  }
  if (t == 1023) off[N] = sums[1023];
}

__global__ __launch_bounds__(256) void k_fill(const int* __restrict__ ei,
                                              const int* __restrict__ off,
                                              int* __restrict__ cur,
                                              int2* __restrict__ elist2, int E) {
  int e = blockIdx.x * 256 + threadIdx.x;
  if (e < E) {
    int s = ei[e];
    int d = ei[E + e];
    int pos = off[s] + atomicAdd(&cur[s], 1);
    elist2[pos] = make_int2(e, d);
  }
}

// ---------------------------------------------------------------------------
// Edge MLP via MFMA bf16 (fp32 accum). Block = 64 edges, 4 waves.
// Output fa[E][64][4] bf16 = (f0,f1,f2,0) per channel, coalesced via LDS h3.
// ---------------------------------------------------------------------------
__global__ __launch_bounds__(256) void k_mlp(
    const float* __restrict__ ew, const float* __restrict__ ea,
    const float* __restrict__ b1, const float* __restrict__ b2,
    const float* __restrict__ b3, const unsigned short* __restrict__ Wf,
    unsigned short* __restrict__ fa, int E) {
  __shared__ __align__(16) char smem[31744];
  unsigned short (*attrB)[40] = (unsigned short(*)[40])smem;            // [64][40]
  unsigned short (*h1B)[72]   = (unsigned short(*)[72])(smem + 5120);   // [64][72]
  unsigned short (*h2B)[136]  = (unsigned short(*)[136])(smem + 14336); // [64][136]
  unsigned short (*h3)[200]   = (unsigned short(*)[200])smem;           // alias (phase 4)
  __shared__ float cws[64];
  const int e0 = blockIdx.x * 64;
  const int tid = threadIdx.x;

  { // stage edge_attr -> bf16 LDS (4 threads/edge)
    int e = tid >> 2, q = tid & 3;
    int ge = e0 + e;
    uint4 pk;
    if (ge < E) {
      const float4* p = (const float4*)(ea + (size_t)ge * R + q * 8);
      float4 x0 = p[0], x1 = p[1];
      pk.x = (unsigned)f2bfu(x0.x) | ((unsigned)f2bfu(x0.y) << 16);
      pk.y = (unsigned)f2bfu(x0.z) | ((unsigned)f2bfu(x0.w) << 16);
      pk.z = (unsigned)f2bfu(x1.x) | ((unsigned)f2bfu(x1.y) << 16);
      pk.w = (unsigned)f2bfu(x1.z) | ((unsigned)f2bfu(x1.w) << 16);
    } else {
      pk = make_uint4(0, 0, 0, 0);
    }
    *(uint4*)&attrB[e][q * 8] = pk;
  }
  if (tid < 64) {
    int ge = e0 + tid;
    float wgt = (ge < E) ? ew[ge] : 1e9f;
    float cc = 0.5f * (cosf(wgt * (PI_F / CUTOFF)) + 1.0f);
    cws[tid] = (wgt < CUTOFF) ? cc : 0.f;
  }
  __syncthreads();

  const int l = tid & 63, wv = tid >> 6;
  const int g = l >> 4, r = l & 15;
  const int mrow = 16 * wv + r;

  const short8b* WfL1 = (const short8b*)Wf;
  const short8b* WfL2 = WfL1 + 256;
  const short8b* WfL3 = WfL1 + 1280;

  // ---- layer 1: 32 -> 64 ----
  f32x4 acc1[4];
#pragma unroll
  for (int nt = 0; nt < 4; nt++) {
    float b = b1[nt * 16 + r];
    acc1[nt] = (f32x4){b, b, b, b};
  }
  {
    const unsigned short* arow = &attrB[mrow][0];
    short4b lo = *(const short4b*)(arow + g * 4);
    short4b hi = *(const short4b*)(arow + 16 + g * 4);
    short8b a = __builtin_shufflevector(lo, hi, 0, 1, 2, 3, 4, 5, 6, 7);
#pragma unroll
    for (int nt = 0; nt < 4; nt++)
      acc1[nt] = __builtin_amdgcn_mfma_f32_16x16x32_bf16(a, WfL1[nt * 64 + l], acc1[nt], 0, 0, 0);
  }
#pragma unroll
  for (int nt = 0; nt < 4; nt++)
#pragma unroll
    for (int reg = 0; reg < 4; reg++)
      h1B[16 * wv + g * 4 + reg][nt * 16 + r] = f2bfu(silu(acc1[nt][reg]));
  __syncthreads();

  // ---- layer 2: 64 -> 128 ----
  f32x4 acc2[8];
#pragma unroll
  for (int nt = 0; nt < 8; nt++) {
    float b = b2[nt * 16 + r];
    acc2[nt] = (f32x4){b, b, b, b};
  }
#pragma unroll
  for (int s = 0; s < 2; s++) {
    const unsigned short* hrow = &h1B[mrow][s * 32];
    short4b lo = *(const short4b*)(hrow + g * 4);
    short4b hi = *(const short4b*)(hrow + 16 + g * 4);
    short8b a = __builtin_shufflevector(lo, hi, 0, 1, 2, 3, 4, 5, 6, 7);
#pragma unroll
    for (int nt = 0; nt < 8; nt++)
      acc2[nt] = __builtin_amdgcn_mfma_f32_16x16x32_bf16(a, WfL2[(s * 8 + nt) * 64 + l], acc2[nt], 0, 0, 0);
  }
#pragma unroll
  for (int nt = 0; nt < 8; nt++)
#pragma unroll
    for (int reg = 0; reg < 4; reg++)
      h2B[16 * wv + g * 4 + reg][nt * 16 + r] = f2bfu(silu(acc2[nt][reg]));
  __syncthreads();

  // ---- layer 3: 128 -> 192 ----
  f32x4 acc3[12];
#pragma unroll
  for (int nt = 0; nt < 12; nt++) {
    float b = b3[nt * 16 + r];
    acc3[nt] = (f32x4){b, b, b, b};
  }
#pragma unroll
  for (int s = 0; s < 4; s++) {
    const unsigned short* hrow = &h2B[mrow][s * 32];
    short4b lo = *(const short4b*)(hrow + g * 4);
    short4b hi = *(const short4b*)(hrow + 16 + g * 4);
    short8b a = __builtin_shufflevector(lo, hi, 0, 1, 2, 3, 4, 5, 6, 7);
#pragma unroll
    for (int nt = 0; nt < 12; nt++)
      acc3[nt] = __builtin_amdgcn_mfma_f32_16x16x32_bf16(a, WfL3[(s * 12 + nt) * 64 + l], acc3[nt], 0, 0, 0);
  }
  __syncthreads();   // all h2B reads done; safe to alias with h3

  // ---- phase 4: h3 (bf16, *cw) -> LDS, then coalesced repack to fa ----
  {
    float cwr[4];
#pragma unroll
    for (int reg = 0; reg < 4; reg++) cwr[reg] = cws[16 * wv + g * 4 + reg];
#pragma unroll
    for (int nt = 0; nt < 12; nt++) {
      int n = nt * 16 + r;
#pragma unroll
      for (int reg = 0; reg < 4; reg++)
        h3[16 * wv + g * 4 + reg][n] = f2bfu(silu(acc3[nt][reg]) * cwr[reg]);
    }
  }
  __syncthreads();
  {
#pragma unroll
    for (int s2 = 0; s2 < 8; s2++) {
      int gbyte = s2 * 4096 + tid * 16;
      int e = gbyte >> 9;
      int off8 = gbyte & 511;
      int ch0 = off8 >> 3;            // even
      int ge = e0 + e;
      if (ge < E) {
        const unsigned* hp = (const unsigned*)&h3[e][3 * ch0];
        unsigned u0 = hp[0], u1 = hp[1], u2 = hp[2];
        uint4 v = make_uint4(u0, u1 & 0xffffu, (u1 >> 16) | (u2 << 16), u2 >> 16);
        *(uint4*)((char*)fa + (size_t)ge * 512 + off8) = v;
      }
    }
  }
}

// ---------------------------------------------------------------------------
// Fused gather + output. Block = 2 nodes x 2 waves. Each wave accumulates
// over half the node's CSR edges with a 2-stage prefetch pipeline; partials
// reduced in LDS; sub-wave 0 runs the epilogue.
// ---------------------------------------------------------------------------
__global__ __launch_bounds__(256) void k_gather_out(
    const int2* __restrict__ elist2, const int* __restrict__ off,
    const unsigned short* __restrict__ fa,
    const float* __restrict__ nf, const float* __restrict__ Xn,
    const float* __restrict__ Wt, float* __restrict__ out, int N) {
  const int wv  = threadIdx.x >> 6;
  const int c   = threadIdx.x & 63;
  const int nl  = wv >> 1, sub = wv & 1;
  const int node = blockIdx.x * 2 + nl;
  __shared__ float part[2][64][9];
  __shared__ float comps[2][C][12];

  float m[9];
#pragma unroll
  for (int j = 0; j < 9; j++) m[j] = 0.f;

  if (node < N) {
    const int tEnd = off[node + 1];
    int idx = off[node] + sub;
    if (idx < tEnd) {
      int2 ed = elist2[idx];
      uint2 f = *(const uint2*)(fa + ((size_t)ed.x << 8) + (c << 2));
      const float* p = nf + (size_t)ed.y * 768 + c * 12;
      float4 q0 = *(const float4*)p;
      float4 q1 = *(const float4*)(p + 4);
      float2 q2 = *(const float2*)(p + 8);
      while (true) {
        idx += 2;
        bool more = idx < tEnd;
        uint2 fn; float4 q0n, q1n; float2 q2n;
        if (more) {
          int2 edn = elist2[idx];
          fn = *(const uint2*)(fa + ((size_t)edn.x << 8) + (c << 2));
          const float* pn = nf + (size_t)edn.y * 768 + c * 12;
          q0n = *(const float4*)pn;
          q1n = *(const float4*)(pn + 4);
          q2n = *(const float2*)(pn + 8);
        }
        float f0 = bfu2f((unsigned short)(f.x & 0xffffu));
        float f1 = bfu2f((unsigned short)(f.x >> 16));
        float f2 = bfu2f((unsigned short)(f.y & 0xffffu));
        float iv = q0.x, a0 = q0.y, a1 = q0.z, a2 = q0.w;
        float s00 = q1.x, s11 = q1.y, s22 = q1.z, s01 = q1.w;
        float s02 = q2.x, s12 = q2.y;
        float d0 = f0 * iv;
        m[0] += d0 + f2 * s00; m[4] += d0 + f2 * s11; m[8] += d0 + f2 * s22;
        float A01 = f1 * a0, A02 = f1 * a1, A12 = f1 * a2;
        float S01 = f2 * s01, S02 = f2 * s02, S12 = f2 * s12;
        m[1] += A01 + S01; m[3] += S01 - A01;
        m[2] += A02 + S02; m[6] += S02 - A02;
        m[5] += A12 + S12; m[7] += S12 - A12;
        if (!more) break;
        f = fn; q0 = q0n; q1 = q1n; q2 = q2n;
      }
    }
  }

  if (sub == 1 && node < N) {
#pragma unroll
    for (int j = 0; j < 9; j++) part[nl][c][j] = m[j];
  }
  __syncthreads();
  if (sub == 0 && node < N) {
#pragma unroll
    for (int j = 0; j < 9; j++) m[j] += part[nl][c][j];
    const float* p = nf + (size_t)node * 768 + c * 12;
    float4 q0 = *(const float4*)p;
    float4 q1 = *(const float4*)(p + 4);
    float2 q2 = *(const float2*)(p + 8);
    float iv = q0.x, a0 = q0.y, a1 = q0.z, a2 = q0.w;
    float s00 = q1.x, s11 = q1.y, s22 = q1.z, s01 = q1.w;
    float s02 = q2.x, s12 = q2.y;
    float Y[9] = { iv + s00, a0 + s01, a1 + s02,
                   s01 - a0, iv + s11, a2 + s12,
                   s02 - a1, s12 - a2, iv + s22 };
    float M[9];
#pragma unroll
    for (int i2 = 0; i2 < 3; i2++)
#pragma unroll
      for (int j2 = 0; j2 < 3; j2++) {
        float acc = 0.f;
#pragma unroll
        for (int k2 = 0; k2 < 3; k2++)
          acc += m[i2 * 3 + k2] * Y[k2 * 3 + j2] + Y[i2 * 3 + k2] * m[k2 * 3 + j2];
        M[i2 * 3 + j2] = acc;
      }
    float nrm = 0.f;
#pragma unroll
    for (int j = 0; j < 9; j++) nrm += M[j] * M[j];
    const float inv = 1.0f / (nrm + 1.0f);
    const float tr3 = (M[0] + M[4] + M[8]) * (1.f / 3.f);
    float* cp = comps[nl][c];
    cp[0] = tr3 * inv;
    cp[1] = 0.5f * (M[1] - M[3]) * inv;
    cp[2] = 0.5f * (M[2] - M[6]) * inv;
    cp[3] = 0.5f * (M[5] - M[7]) * inv;
    cp[4] = (M[0] - tr3) * inv;
    cp[5] = (M[4] - tr3) * inv;
    cp[6] = (M[8] - tr3) * inv;
    cp[7] = 0.5f * (M[1] + M[3]) * inv;
    cp[8] = 0.5f * (M[2] + M[6]) * inv;
    cp[9] = 0.5f * (M[5] + M[7]) * inv;
  }
  __syncthreads();
  if (sub == 0 && node < N) {
    const float* W3p = Wt + 3 * C * C;
    const float* W4p = Wt + 4 * C * C;
    const float* W5p = Wt + 5 * C * C;
    float o[10];
#pragma unroll
    for (int j = 0; j < 10; j++) o[j] = 0.f;
    for (int k = 0; k < C; k++) {
      const float w3 = W3p[k * C + c];
      const float w4 = W4p[k * C + c];
      const float w5 = W5p[k * C + c];
      const float4* cq = (const float4*)comps[nl][k];
      float4 q0 = cq[0], q1 = cq[1];
      float2 q2 = *(const float2*)(comps[nl][k] + 8);
      o[0] += q0.x * w3;
      o[1] += q0.y * w4; o[2] += q0.z * w4; o[3] += q0.w * w4;
      o[4] += q1.x * w5; o[5] += q1.y * w5; o[6] += q1.z * w5;
      o[7] += q1.w * w5; o[8] += q2.x * w5; o[9] += q2.y * w5;
    }
    float dX[9] = { o[0] + o[4], o[1] + o[7], o[2] + o[8],
                    o[7] - o[1], o[0] + o[5], o[3] + o[9],
                    o[8] - o[2], o[9] - o[3], o[0] + o[6] };
    float dd[9];
#pragma unroll
    for (int i2 = 0; i2 < 3; i2++)
#pragma unroll
      for (int j2 = 0; j2 < 3; j2++) {
        float acc = 0.f;
#pragma unroll
        for (int k2 = 0; k2 < 3; k2++) acc += dX[i2 * 3 + k2] * dX[k2 * 3 + j2];
        dd[i2 * 3 + j2] = acc;
      }
    const float* xnp = Xn + (size_t)node * 576 + c;
    float* op = out + ((size_t)node * C + c) * 9;
#pragma unroll
    for (int j = 0; j < 9; j++) op[j] = xnp[j * 64] + dX[j] + dd[j];
  }
}

extern "C" void kernel_launch(void* const* d_in, const int* in_sizes, int n_in,
                              void* d_out, int out_size, void* d_ws, size_t ws_size,
                              hipStream_t stream) {
  const float* X  = (const float*)d_in[0];
  const int*   ei = (const int*)d_in[1];
  const float* ew = (const float*)d_in[2];
  const float* ea = (const float*)d_in[3];
  const float* W1 = (const float*)d_in[4];
  const float* b1 = (const float*)d_in[5];
  const float* W2 = (const float*)d_in[6];
  const float* b2 = (const float*)d_in[7];
  const float* W3 = (const float*)d_in[8];
  const float* b3 = (const float*)d_in[9];
  const float* Wt = (const float*)d_in[10];
  const int N = in_sizes[0] / (C * 9);
  const int E = in_sizes[1] / 2;

  float* nf = (float*)d_ws;                                     // [N][C][12] fp32
  float* Xn = nf + (size_t)N * 768;                             // [N][9][C]
  unsigned short* fa = (unsigned short*)(Xn + (size_t)N * 576); // [E][64][4] bf16
  unsigned short* Wf = fa + (size_t)E * 256;                    // 34816 bf16 frags
  int* deg  = (int*)(Wf + 34816);                               // [N]
  int* off  = deg + N;                                          // [N+1]
  int* cur  = off + N + 1;                                      // [N]
  int2* elist2 = (int2*)(cur + N);                              // [E] (e, dst)

  hipMemsetAsync(deg, 0, (size_t)N * sizeof(int), stream);
  hipMemsetAsync(cur, 0, (size_t)N * sizeof(int), stream);
  k_wprep<<<(34816 + 255) / 256, 256, 0, stream>>>(W1, W2, W3, Wf);
  k_node_prep<<<(N + 3) / 4, 256, 0, stream>>>(X, Wt, Xn, nf, N);
  k_hist<<<(E + 255) / 256, 256, 0, stream>>>(ei, deg, E);
  k_scan<<<1, 1024, 0, stream>>>(deg, off, N);
  k_fill<<<(E + 255) / 256, 256, 0, stream>>>(ei, off, cur, elist2, E);
  k_mlp<<<(E + 63) / 64, 256, 0, stream>>>(ew, ea, b1, b2, b3, Wf, fa, E);
  k_gather_out<<<(N + 1) / 2, 256, 0, stream>>>(elist2, off, fa, nf, Xn, Wt,
                                                (float*)d_out, N);
}